// Round 1
// baseline (858.866 us; speedup 1.0000x reference)
//
#include <hip/hip_runtime.h>
#include <hip/hip_bf16.h>
#include <cstdint>

typedef _Float16 f16;
typedef _Float16 f16x8 __attribute__((ext_vector_type(8)));
typedef float f32x4 __attribute__((ext_vector_type(4)));

#define N_TOK 8192
#define DDIM 2048
#define EXP 8
#define HDIM 1024
#define ODIM 2048

// ---- ws layout (bytes) ----
// xg   : [8192][2048] f16          @ 0          (32 MiB)
// w1g  : [8][1024][2048] f16       @ 33554432   (32 MiB)
// w2g  : [8][2048][1024] f16       @ 67108864   (32 MiB)
// h    : [32768+128][1024] f16     @ 100663296  (64.25 MiB)
// pair : [32768+128] int           @ 168034304
// masks: [8192] u8                 @ 168165888
// meta : off[9] @ +0, tileOff[9] @ +64   @ 168174080
#define WS_NEEDED 168174208ull

__device__ __forceinline__ void gload_lds16(const void* g, void* l) {
  __builtin_amdgcn_global_load_lds(
      (const __attribute__((address_space(1))) unsigned int*)(unsigned long long)g,
      (__attribute__((address_space(3))) unsigned int*)(unsigned int)(unsigned long long)l,
      16, 0, 0);
}

// ---------------- fp32 -> fp16 convert ----------------
__global__ __launch_bounds__(256) void cvt_kernel(const float* __restrict__ src,
                                                  f16* __restrict__ dst, int n4) {
  int i = blockIdx.x * 256 + threadIdx.x;
  if (i < n4) {
    float4 v = ((const float4*)src)[i];
    union { f16 h[4]; uint2 u; } p;
    p.h[0] = (f16)v.x; p.h[1] = (f16)v.y; p.h[2] = (f16)v.z; p.h[3] = (f16)v.w;
    ((uint2*)dst)[i] = p.u;
  }
}

// ---------------- gate + top-4 mask ----------------
__global__ __launch_bounds__(256) void gate_topk(const float* __restrict__ x,
                                                 const float* __restrict__ wg,
                                                 unsigned char* __restrict__ masks) {
  int wave = threadIdx.x >> 6, lane = threadIdx.x & 63;
  int t = blockIdx.x * 4 + wave;
  const float* xr = x + (size_t)t * DDIM;
  float acc[8];
#pragma unroll
  for (int e = 0; e < 8; e++) acc[e] = 0.f;
#pragma unroll 4
  for (int i = 0; i < 32; i++) {
    int d = i * 64 + lane;
    float xv = xr[d];
    const float4* wrow = (const float4*)(wg + d * 8);
    float4 w0 = wrow[0], w1 = wrow[1];
    acc[0] += xv * w0.x; acc[1] += xv * w0.y; acc[2] += xv * w0.z; acc[3] += xv * w0.w;
    acc[4] += xv * w1.x; acc[5] += xv * w1.y; acc[6] += xv * w1.z; acc[7] += xv * w1.w;
  }
#pragma unroll
  for (int off = 1; off < 64; off <<= 1) {
#pragma unroll
    for (int e = 0; e < 8; e++) acc[e] += __shfl_xor(acc[e], off);
  }
  if (lane == 0) {
    unsigned chosen = 0;
#pragma unroll
    for (int k = 0; k < 4; k++) {
      int best = -1; float bv = 0.f;
      for (int e = 0; e < 8; e++) {
        if (!((chosen >> e) & 1) && (best < 0 || acc[e] > bv)) { bv = acc[e]; best = e; }
      }
      chosen |= 1u << best;
    }
    masks[t] = (unsigned char)chosen;
  }
}

// ---------------- counts -> offsets (1 block) ----------------
__global__ __launch_bounds__(256) void compute_offsets(const unsigned char* __restrict__ masks,
                                                       int* __restrict__ off,
                                                       int* __restrict__ tileOff) {
  __shared__ int cnt[8];
  if (threadIdx.x < 8) cnt[threadIdx.x] = 0;
  __syncthreads();
  int local[8] = {0, 0, 0, 0, 0, 0, 0, 0};
  for (int i = threadIdx.x; i < N_TOK; i += 256) {
    unsigned m = masks[i];
#pragma unroll
    for (int e = 0; e < 8; e++) local[e] += (m >> e) & 1;
  }
#pragma unroll
  for (int e = 0; e < 8; e++)
    if (local[e]) atomicAdd(&cnt[e], local[e]);
  __syncthreads();
  if (threadIdx.x == 0) {
    int o = 0, t = 0;
#pragma unroll
    for (int e = 0; e < 8; e++) {
      off[e] = o; tileOff[e] = t;
      o += cnt[e]; t += (cnt[e] + 127) >> 7;
    }
    off[8] = o; tileOff[8] = t;
  }
}

// ---------------- deterministic per-expert token lists ----------------
__global__ __launch_bounds__(256) void build_lists(const unsigned char* __restrict__ masks,
                                                   const int* __restrict__ off,
                                                   int* __restrict__ pairTok) {
  int e = blockIdx.x;
  __shared__ int tc[256];
  int t0 = threadIdx.x * 32;
  int cnt = 0;
  for (int i = 0; i < 32; i++) cnt += (masks[t0 + i] >> e) & 1;
  tc[threadIdx.x] = cnt;
  __syncthreads();
  for (int d = 1; d < 256; d <<= 1) {
    int v = (threadIdx.x >= d) ? tc[threadIdx.x - d] : 0;
    __syncthreads();
    tc[threadIdx.x] += v;
    __syncthreads();
  }
  int pos = off[e] + tc[threadIdx.x] - cnt;
  for (int i = 0; i < 32; i++) {
    if ((masks[t0 + i] >> e) & 1) pairTok[pos++] = t0 + i;
  }
}

// ---------------- grouped expert GEMM ----------------
// PHASE1: h[s][0:1024] = relu( x[pairTok[s]][:] . w1[e][n][:] )    K=2048, NDIM=1024
// PHASE2: out[pairTok[s]][n] += h[s][:] . w2[e][n][:]  (atomic)    K=1024, NDIM=2048
// 128x128 tile, BK=64, 4 waves (2x2 of 64x64), mfma_f32_16x16x32_f16,
// XOR-swizzled LDS (byte ^= (row&7)<<4) with pre-swizzled global source (T2/m201 pattern).
template <int K, int NDIM, bool PHASE1>
__global__ __launch_bounds__(256) void gemm_expert(const f16* __restrict__ Asrc,
                                                   const f16* __restrict__ Wsrc,
                                                   const int* __restrict__ off,
                                                   const int* __restrict__ tileOff,
                                                   const int* __restrict__ pairTok,
                                                   f16* __restrict__ hout,
                                                   float* __restrict__ out) {
  int to[9];
#pragma unroll
  for (int i = 0; i < 9; i++) to[i] = tileOff[i];
  int ft = blockIdx.x;
  if (ft >= to[8]) return;
  int e = 0;
#pragma unroll
  for (int i = 1; i < 8; i++)
    if (ft >= to[i]) e = i;
  int s0 = off[e] + (ft - to[e]) * 128;
  int sEnd = off[e + 1];
  int n0 = blockIdx.y * 128;

  const int tid = threadIdx.x;
  const int wave = tid >> 6, lane = tid & 63;

  __shared__ __align__(16) char smem[2 * 32768];

  // 8 chunks of 16B per thread: bytes [c*4096 + tid*16]; A tile = bytes [0,16384), B = [16384,32768)
  const char* gbase[8];
#pragma unroll
  for (int c = 0; c < 8; c++) {
    int bo = c * 4096 + tid * 16;
    int r = (bo & 16383) >> 7;     // row within tile
    int cb = bo & 127;             // col byte (16-aligned)
    int scb = cb ^ ((r & 7) << 4); // inverse-swizzled source col
    if (c < 4) {
      long row;
      if (PHASE1) {
        int s = s0 + r;
        int sEff = s < sEnd ? s : s0;
        row = pairTok[sEff];
      } else {
        row = s0 + r; // h rows are slot-indexed; padded allocation
      }
      gbase[c] = (const char*)Asrc + (size_t)row * (K * 2) + scb;
    } else {
      gbase[c] = (const char*)Wsrc + ((size_t)e * NDIM + n0 + r) * (K * 2) + scb;
    }
  }

  auto stage = [&](int buf, int k0) {
    size_t kb = (size_t)k0 * 2;
#pragma unroll
    for (int c = 0; c < 8; c++) {
      void* lds = smem + buf * 32768 + c * 4096 + (wave << 10);
      gload_lds16(gbase[c] + kb, lds);
    }
  };

  f32x4 acc[4][4];
  const f32x4 zero = {0.f, 0.f, 0.f, 0.f};
#pragma unroll
  for (int m = 0; m < 4; m++)
#pragma unroll
    for (int n = 0; n < 4; n++) acc[m][n] = zero;

  const int wr = (wave >> 1) * 64, wc = (wave & 1) * 64;
  const int fr = lane & 15, fg = lane >> 4;

  int arow[4], brow[4];
#pragma unroll
  for (int m = 0; m < 4; m++) arow[m] = wr + m * 16 + fr;
#pragma unroll
  for (int n = 0; n < 4; n++) brow[n] = wc + n * 16 + fr;

  stage(0, 0);
  const int KT = K / 64;
  for (int kt = 0; kt < KT; kt++) {
    if (kt + 1 < KT) stage((kt + 1) & 1, (kt + 1) * 64);
    __syncthreads();
    const char* bp = smem + (kt & 1) * 32768;
#pragma unroll
    for (int ks = 0; ks < 2; ks++) {
      f16x8 af[4], bf[4];
      int kb = ks * 64 + fg * 16;
#pragma unroll
      for (int m = 0; m < 4; m++)
        af[m] = *(const f16x8*)(bp + arow[m] * 128 + (kb ^ ((arow[m] & 7) << 4)));
#pragma unroll
      for (int n = 0; n < 4; n++)
        bf[n] = *(const f16x8*)(bp + 16384 + brow[n] * 128 + (kb ^ ((brow[n] & 7) << 4)));
#pragma unroll
      for (int m = 0; m < 4; m++)
#pragma unroll
        for (int n = 0; n < 4; n++)
          acc[m][n] = __builtin_amdgcn_mfma_f32_16x16x32_f16(af[m], bf[n], acc[m][n], 0, 0, 0);
    }
    __syncthreads();
  }

  // epilogue: C/D layout col=lane&15, row=(lane>>4)*4+reg  [m89-verified]
#pragma unroll
  for (int m = 0; m < 4; m++) {
#pragma unroll
    for (int j = 0; j < 4; j++) {
      int rl = wr + m * 16 + fg * 4 + j;
      int s = s0 + rl;
      if (s < sEnd) {
        if (PHASE1) {
          size_t base = (size_t)s * NDIM + n0;
#pragma unroll
          for (int n = 0; n < 4; n++) {
            float v = acc[m][n][j];
            hout[base + wc + n * 16 + fr] = (f16)(v > 0.f ? v : 0.f);
          }
        } else {
          int tok = pairTok[s];
          size_t base = (size_t)tok * ODIM + n0;
#pragma unroll
          for (int n = 0; n < 4; n++)
            atomicAdd(&out[base + wc + n * 16 + fr], acc[m][n][j]);
        }
      }
    }
  }
}

extern "C" void kernel_launch(void* const* d_in, const int* in_sizes, int n_in,
                              void* d_out, int out_size, void* d_ws, size_t ws_size,
                              hipStream_t stream) {
  const float* x = (const float*)d_in[0];
  const float* wg = (const float*)d_in[1];
  const float* w1 = (const float*)d_in[2];
  const float* w2 = (const float*)d_in[3];
  float* out = (float*)d_out;

  if (ws_size < WS_NEEDED) return; // loud failure signal (output stays poison/zero)

  char* ws = (char*)d_ws;
  f16* xg = (f16*)(ws + 0);
  f16* w1g = (f16*)(ws + 33554432);
  f16* w2g = (f16*)(ws + 67108864);
  f16* h = (f16*)(ws + 100663296);
  int* pairTok = (int*)(ws + 168034304);
  unsigned char* masks = (unsigned char*)(ws + 168165888);
  int* off = (int*)(ws + 168174080);
  int* tileOff = off + 16;

  hipMemsetAsync(d_out, 0, (size_t)N_TOK * ODIM * 4, stream);

  cvt_kernel<<<16384, 256, 0, stream>>>(x, xg, 4194304);
  cvt_kernel<<<16384, 256, 0, stream>>>(w1, w1g, 4194304);
  cvt_kernel<<<16384, 256, 0, stream>>>(w2, w2g, 4194304);
  gate_topk<<<2048, 256, 0, stream>>>(x, wg, masks);
  compute_offsets<<<1, 256, 0, stream>>>(masks, off, tileOff);
  build_lists<<<8, 256, 0, stream>>>(masks, off, pairTok);

  dim3 g1(263, 8), g2(263, 16);
  gemm_expert<2048, 1024, true><<<g1, 256, 0, stream>>>(xg, w1g, off, tileOff, pairTok, h, nullptr);
  gemm_expert<1024, 2048, false><<<g2, 256, 0, stream>>>(h, w2g, off, tileOff, pairTok, nullptr, out);
}